// Round 3
// baseline (349.026 us; speedup 1.0000x reference)
//
#include <hip/hip_runtime.h>
#include <stdint.h>

// Problem constants (fixed by the reference file)
#define T_TOTAL  4194304          // B*K*N = 8*4*131072
#define NEG_IDLE (-100000000.0f)
#define NEG_FILL (-1000.0f)

#define BLOCK   256
#define EPT     16
#define EPB     (BLOCK * EPT)       // 4096
#define NBLOCKS (T_TOTAL / EPB)     // 1024
// N = 131072 = 32*4096 -> each block has one uniform (b,k): bk = blk >> 5

// Decoupled-lookback slot encoding (single 64-bit atomic word):
//   [1:0]   state: 0 = invalid (poison-cleared), 1 = aggregate, 2 = prefix
//   [25:2]  surface count (<= 2^22 total, fits 24-bit field, no carry-out)
//   [49:26] air count
#define ST_AGG 1ull
#define ST_PRE 2ull

__device__ __forceinline__ uint64_t pack_counts(uint32_t cs, uint32_t ca) {
    return ((uint64_t)cs << 2) | ((uint64_t)ca << 26);
}

// 16 consecutive int32 bool elements -> 16-bit mask (jnp bool arrives as int32)
__device__ __forceinline__ unsigned int decode16_i32(const uint4* p) {
    unsigned int bits = 0;
    #pragma unroll
    for (int q = 0; q < 4; ++q) {
        const uint4 v = p[q];
        bits |= (v.x ? 1u : 0u) << (4 * q + 0);
        bits |= (v.y ? 1u : 0u) << (4 * q + 1);
        bits |= (v.z ? 1u : 0u) << (4 * q + 2);
        bits |= (v.w ? 1u : 0u) << (4 * q + 3);
    }
    return bits;
}

// ---------------------------------------------------------------------------
// Kernel 0: clear lookback slots (d_ws is re-poisoned to 0xAA every launch,
// and 0xAA..AA decodes as state=2 (prefix) -> must zero before main kernel)
// ---------------------------------------------------------------------------
__global__ __launch_bounds__(BLOCK) void init_kernel(unsigned long long* slots) {
    const int i = blockIdx.x * BLOCK + threadIdx.x;
    if (i < NBLOCKS) slots[i] = 0ull;
}

// ---------------------------------------------------------------------------
// Fused single-pass kernel: decode + local scan + decoupled lookback +
// gather + scale + select + vectorized stores.
// __launch_bounds__(256,6): VGPR<=85 -> >=6 blocks/CU -> capacity 1536 >= 1024
// grid => ALL blocks co-resident => lookback spin cannot deadlock.
// ---------------------------------------------------------------------------
__global__ __launch_bounds__(BLOCK, 6) void fused_kernel(
    const float* __restrict__ rgb,
    const float* __restrict__ ls,
    const float* __restrict__ la,
    const uint4* __restrict__ ms,     // int32 bools, viewed as uint4 (4 elems)
    const uint4* __restrict__ ma,
    const float* __restrict__ idle_states,
    unsigned long long* __restrict__ slots,
    float* __restrict__ out)
{
    const int blk  = blockIdx.x;
    const int tid  = threadIdx.x;
    const int lane = tid & 63;
    const int wave = tid >> 6;
    const size_t base = (size_t)blk * EPB + (size_t)tid * EPT;

    // ---- decode masks (16 elems/thread) ----
    const unsigned int bits_s = decode16_i32(ms + (base >> 2));
    const unsigned int bits_a = decode16_i32(ma + (base >> 2));
    const int cs = __popc(bits_s);
    const int ca = __popc(bits_a);

    // ---- wave-level inclusive scan of packed (air<<32 | surf) ----
    const unsigned long long pk = ((unsigned long long)(unsigned)ca << 32) | (unsigned)cs;
    unsigned long long incl = pk;
    #pragma unroll
    for (int d = 1; d < 64; d <<= 1) {
        unsigned long long t = __shfl_up(incl, d, 64);
        if (lane >= d) incl += t;
    }
    unsigned long long excl = incl - pk;

    __shared__ unsigned long long wtot[BLOCK / 64];
    __shared__ unsigned long long sPre;   // packed exclusive prefix for block
    if (lane == 63) wtot[wave] = incl;
    __syncthreads();
    #pragma unroll
    for (int w = 0; w < BLOCK / 64; ++w)
        if (w < wave) excl += wtot[w];

    // block aggregate (uniform across threads after barrier)
    const unsigned long long tot = wtot[0] + wtot[1] + wtot[2] + wtot[3];
    const uint64_t aggpack = pack_counts((uint32_t)tot, (uint32_t)(tot >> 32));

    // ---- publish aggregate, then wave 0 does the lookback ----
    if (tid == 0) {
        const uint64_t val = aggpack | ((blk == 0) ? ST_PRE : ST_AGG);
        __hip_atomic_store(&slots[blk], val, __ATOMIC_RELEASE, __HIP_MEMORY_SCOPE_AGENT);
        if (blk == 0) sPre = 0ull;
    }
    if (blk != 0 && wave == 0) {
        int look = blk - 1;
        uint64_t acc = 0;
        for (;;) {
            const int src = look - lane;           // lane 0 = nearest predecessor
            uint64_t v;
            for (;;) {                             // poll until window fully valid
                v = (src >= 0)
                    ? __hip_atomic_load(&slots[src], __ATOMIC_ACQUIRE, __HIP_MEMORY_SCOPE_AGENT)
                    : ST_PRE;                      // virtual block -1: prefix 0
                if (__all((v & 3ull) != 0ull)) break;
                __builtin_amdgcn_s_sleep(1);
            }
            const unsigned long long pm = __ballot((v & 3ull) == ST_PRE);
            uint64_t contrib = v & ~3ull;
            int L = -1;
            if (pm) {
                L = __ffsll((long long)pm) - 1;    // nearest prefix
                if (lane > L) contrib = 0;         // lanes < L are aggregates
            }
            uint64_t s = contrib;
            #pragma unroll
            for (int d = 32; d; d >>= 1) s += __shfl_down(s, d, 64);
            acc += __shfl(s, 0, 64);
            if (pm) break;
            look -= 64;
        }
        if (lane == 0) {
            sPre = acc;
            __hip_atomic_store(&slots[blk], (acc + aggpack) | ST_PRE,
                               __ATOMIC_RELEASE, __HIP_MEMORY_SCOPE_AGENT);
        }
    }
    __syncthreads();

    const uint64_t pre = sPre;
    int idx_s = (int)((pre >> 2)  & 0xFFFFFFull) + (int)(excl & 0xffffffffULL);
    int idx_a = (int)((pre >> 26) & 0xFFFFFFull) + (int)(excl >> 32);

    // entire block shares one (b,k)
    const float idle      = idle_states[blk >> 5];
    const float scale     = 1.0f - idle;
    const float idle_term = idle * NEG_IDLE;

    float4* prgb = (float4*)(out + base * 3);                     // 192B/thread
    float4* pls  = (float4*)(out + (size_t)3 * T_TOTAL + base);   //  64B/thread
    float4* pla  = (float4*)(out + (size_t)4 * T_TOTAL + base);

    #pragma unroll
    for (int g = 0; g < 4; ++g) {        // groups of 4 elems: keeps VGPRs low
        float og[12], sg[4], ag[4];
        #pragma unroll
        for (int jj = 0; jj < 4; ++jj) {
            const int j = g * 4 + jj;
            const bool bs = (bits_s >> j) & 1u;
            const bool ba = (bits_a >> j) & 1u;

            // Branchless: idx always in-bounds (excl prefix <= elem pos < T)
            const float* rp = rgb + (size_t)idx_s * 3;
            const float r0 = rp[0], r1 = rp[1], r2 = rp[2];
            const float lsv = ls[idx_s];
            const float lav = la[idx_a];

            og[jj * 3 + 0] = bs ? r0 * scale : 0.0f;
            og[jj * 3 + 1] = bs ? r1 * scale : 0.0f;
            og[jj * 3 + 2] = bs ? r2 * scale : 0.0f;
            sg[jj] = bs ? (lsv * scale + idle_term) : NEG_FILL;
            ag[jj] = ba ? (lav * scale + idle_term) : NEG_FILL;

            idx_s += bs ? 1 : 0;
            idx_a += ba ? 1 : 0;
        }
        prgb[g * 3 + 0] = ((const float4*)og)[0];
        prgb[g * 3 + 1] = ((const float4*)og)[1];
        prgb[g * 3 + 2] = ((const float4*)og)[2];
        pls[g] = ((const float4*)sg)[0];
        pla[g] = ((const float4*)ag)[0];
    }
}

// ---------------------------------------------------------------------------
extern "C" void kernel_launch(void* const* d_in, const int* in_sizes, int n_in,
                              void* d_out, int out_size, void* d_ws, size_t ws_size,
                              hipStream_t stream) {
    const float* rgb  = (const float*)d_in[0];
    const float* ls   = (const float*)d_in[1];
    const float* la   = (const float*)d_in[2];
    const uint4* ms   = (const uint4*)d_in[3];   // jnp bool -> int32 on device
    const uint4* ma   = (const uint4*)d_in[4];
    const float* idle = (const float*)d_in[5];
    float* out = (float*)d_out;

    unsigned long long* slots = (unsigned long long*)d_ws;

    init_kernel<<<(NBLOCKS + BLOCK - 1) / BLOCK, BLOCK, 0, stream>>>(slots);
    fused_kernel<<<NBLOCKS, BLOCK, 0, stream>>>(rgb, ls, la, ms, ma, idle,
                                                slots, out);
}

// Round 4
// 185.309 us; speedup vs baseline: 1.8835x; 1.8835x over previous
//
#include <hip/hip_runtime.h>
#include <stdint.h>

// Problem constants (fixed by the reference file)
#define T_TOTAL  4194304          // B*K*N = 8*4*131072
#define NEG_IDLE (-100000000.0f)
#define NEG_FILL (-1000.0f)

#define BLOCK   256
#define EPT     8
#define EPB     (BLOCK * EPT)       // 2048 elements per block
#define NBLOCKS (T_TOTAL / EPB)     // 2048 blocks
// N = 131072 = 64 * 2048 -> each block has one uniform (b,k): bk = blk >> 6

// Workspace layout:
//   [0 .. 16K)      : sums[2048]  u64 packed (surf count low32, air high32)
//   [16K .. 16K+1M) : packed bits, u16 per thread (surf low8 | air<<8)
// K1 fully writes both regions before K2 reads them (stream order), so the
// 0xAA re-poison of d_ws needs no separate init kernel.

// 8 consecutive int32 bool elements -> 8-bit mask (jnp bool arrives as int32)
__device__ __forceinline__ unsigned decode8_i32(const uint4* p) {
    const uint4 a = p[0], b = p[1];
    return (a.x ? 1u : 0u) | (a.y ? 2u : 0u) | (a.z ? 4u : 0u) | (a.w ? 8u : 0u)
         | (b.x ? 16u : 0u) | (b.y ? 32u : 0u) | (b.z ? 64u : 0u) | (b.w ? 128u : 0u);
}

// ---------------------------------------------------------------------------
// Kernel 1: per-block mask popcounts + bit-repack (1 barrier)
// ---------------------------------------------------------------------------
__global__ __launch_bounds__(BLOCK) void reduce_pack_kernel(
    const uint4* __restrict__ ms,
    const uint4* __restrict__ ma,
    unsigned long long* __restrict__ sums,
    unsigned short* __restrict__ packed)
{
    const int blk  = blockIdx.x;
    const int tid  = threadIdx.x;
    const int lane = tid & 63;
    const int wave = tid >> 6;
    const size_t e = (size_t)blk * EPB + (size_t)tid * EPT;

    const unsigned bits_s = decode8_i32(ms + (e >> 2));
    const unsigned bits_a = decode8_i32(ma + (e >> 2));
    packed[blk * BLOCK + tid] = (unsigned short)(bits_s | (bits_a << 8));

    unsigned long long v =
        ((unsigned long long)(unsigned)__popc(bits_a) << 32) | (unsigned)__popc(bits_s);
    #pragma unroll
    for (int d = 32; d; d >>= 1) v += __shfl_down(v, d, 64);

    __shared__ unsigned long long w[BLOCK / 64];
    if (lane == 0) w[wave] = v;
    __syncthreads();
    if (tid == 0) sums[blk] = w[0] + w[1] + w[2] + w[3];
}

// ---------------------------------------------------------------------------
// Kernel 2: per-block prefix (own reduction over sums[] from L2) + local scan
// + gather + scale + select + vectorized stores. Indices are popcount-derived
// (no serial chain); all gathers issue before any select/store.
// ---------------------------------------------------------------------------
__global__ __launch_bounds__(BLOCK) void scatter_kernel(
    const float* __restrict__ rgb,
    const float* __restrict__ ls,
    const float* __restrict__ la,
    const unsigned long long* __restrict__ sums,
    const unsigned short* __restrict__ packed,
    const float* __restrict__ idle_states,
    float* __restrict__ out)
{
    const int blk  = blockIdx.x;
    const int tid  = threadIdx.x;
    const int lane = tid & 63;
    const int wave = tid >> 6;
    const size_t base = (size_t)blk * EPB + (size_t)tid * EPT;

    // ---- masks ----
    const unsigned p = packed[blk * BLOCK + tid];
    const unsigned bits_s = p & 0xffu;
    const unsigned bits_a = p >> 8;

    // ---- block prefix: every thread reduces its slice of sums[0..blk-1] ----
    // 2048 u64 = 16 KB, L2-resident; thread t covers indices 8t..8t+7.
    unsigned long long acc = 0;
    {
        const ulonglong2* s2 = (const ulonglong2*)sums;
        const int i0 = tid * 8;
        #pragma unroll
        for (int q = 0; q < 4; ++q) {
            const ulonglong2 v = s2[tid * 4 + q];
            const int i = i0 + 2 * q;
            acc += (i     < blk) ? v.x : 0ull;
            acc += (i + 1 < blk) ? v.y : 0ull;
        }
        #pragma unroll
        for (int d = 32; d; d >>= 1) acc += __shfl_down(acc, d, 64);
    }

    // ---- wave-level inclusive scan of packed (air<<32 | surf) counts ----
    const unsigned long long pk =
        ((unsigned long long)(unsigned)__popc(bits_a) << 32) | (unsigned)__popc(bits_s);
    unsigned long long incl = pk;
    #pragma unroll
    for (int d = 1; d < 64; d <<= 1) {
        unsigned long long t = __shfl_up(incl, d, 64);
        if (lane >= d) incl += t;
    }
    unsigned long long excl = incl - pk;

    __shared__ unsigned long long wtot[BLOCK / 64];
    __shared__ unsigned long long wpre[BLOCK / 64];
    if (lane == 63) wtot[wave] = incl;
    if (lane == 0)  wpre[wave] = acc;
    __syncthreads();
    #pragma unroll
    for (int w = 0; w < BLOCK / 64; ++w)
        if (w < wave) excl += wtot[w];
    const unsigned long long pre = wpre[0] + wpre[1] + wpre[2] + wpre[3];

    const int idx_s0 = (int)((pre + excl) & 0xffffffffULL);
    const int idx_a0 = (int)((pre + excl) >> 32);

    // ---- per-element indices, branch-free, no serial chain ----
    int is_[EPT], ia_[EPT];
    #pragma unroll
    for (int j = 0; j < EPT; ++j) {
        is_[j] = idx_s0 + __popc(bits_s & ((1u << j) - 1u));
        ia_[j] = idx_a0 + __popc(bits_a & ((1u << j) - 1u));
    }

    // ---- issue all gathers (always in-bounds: excl prefix <= elem pos < T) ----
    float r[3 * EPT], sv[EPT], av[EPT];
    #pragma unroll
    for (int j = 0; j < EPT; ++j) {
        const float* rp = rgb + (size_t)is_[j] * 3;
        r[3 * j + 0] = rp[0];
        r[3 * j + 1] = rp[1];
        r[3 * j + 2] = rp[2];
        sv[j] = ls[is_[j]];
        av[j] = la[ia_[j]];
    }

    // ---- select/scale ----
    const float idle      = idle_states[blk >> 6];   // uniform per block
    const float scale     = 1.0f - idle;
    const float idle_term = idle * NEG_IDLE;
    #pragma unroll
    for (int j = 0; j < EPT; ++j) {
        const bool bs = (bits_s >> j) & 1u;
        const bool ba = (bits_a >> j) & 1u;
        r[3 * j + 0] = bs ? r[3 * j + 0] * scale : 0.0f;
        r[3 * j + 1] = bs ? r[3 * j + 1] * scale : 0.0f;
        r[3 * j + 2] = bs ? r[3 * j + 2] * scale : 0.0f;
        sv[j] = bs ? (sv[j] * scale + idle_term) : NEG_FILL;
        av[j] = ba ? (av[j] * scale + idle_term) : NEG_FILL;
    }

    // ---- vectorized stores (per-thread contiguous, 16B-aligned) ----
    float4* prgb = (float4*)(out + base * 3);                    // 96 B/thread
    #pragma unroll
    for (int j = 0; j < 6; ++j) prgb[j] = ((const float4*)r)[j];

    float4* pls = (float4*)(out + (size_t)3 * T_TOTAL + base);   // 32 B/thread
    pls[0] = ((const float4*)sv)[0];
    pls[1] = ((const float4*)sv)[1];

    float4* pla = (float4*)(out + (size_t)4 * T_TOTAL + base);
    pla[0] = ((const float4*)av)[0];
    pla[1] = ((const float4*)av)[1];
}

// ---------------------------------------------------------------------------
extern "C" void kernel_launch(void* const* d_in, const int* in_sizes, int n_in,
                              void* d_out, int out_size, void* d_ws, size_t ws_size,
                              hipStream_t stream) {
    const float* rgb  = (const float*)d_in[0];
    const float* ls   = (const float*)d_in[1];
    const float* la   = (const float*)d_in[2];
    const uint4* ms   = (const uint4*)d_in[3];   // jnp bool -> int32 on device
    const uint4* ma   = (const uint4*)d_in[4];
    const float* idle = (const float*)d_in[5];
    float* out = (float*)d_out;

    unsigned long long* sums   = (unsigned long long*)d_ws;
    unsigned short*     packed = (unsigned short*)((uint8_t*)d_ws + NBLOCKS * sizeof(unsigned long long));

    reduce_pack_kernel<<<NBLOCKS, BLOCK, 0, stream>>>(ms, ma, sums, packed);
    scatter_kernel<<<NBLOCKS, BLOCK, 0, stream>>>(rgb, ls, la, sums, packed,
                                                  idle, out);
}